// Round 11
// baseline (151.607 us; speedup 1.0000x reference)
//
#include <hip/hip_runtime.h>
#include <hip/hip_bf16.h>

typedef __attribute__((ext_vector_type(8))) short bf16x8;
typedef __attribute__((ext_vector_type(4))) float f32x4;

#define KDIM 2048
#define BK 64
#define NT (KDIM / BK)   // 32 K-tiles

__device__ __forceinline__ unsigned short f2bf(float f) {
  union { float fv; unsigned int u; } c; c.fv = f;
  unsigned int u = c.u;
  unsigned int r = (u + 0x7FFFu + ((u >> 16) & 1u)) >> 16;
  return (unsigned short)r;
}

__device__ __forceinline__ float sigm(float z) { return 1.0f / (1.0f + __expf(-z)); }
__device__ __forceinline__ float tanh_fast(float z) { return 1.0f - 2.0f / (__expf(2.0f * z) + 1.0f); }

// x,h f32 -> apack bf16 fragments:
// frag f = (row16*32 + kt)*2 + ks ; elem = f*512 + lane*8 + j ; lane = lg*16 + ll
// value = hx[row16*16 + ll][kt*64 + ks*32 + lg*8 + j]
__global__ void pack_hx_kernel(const float* __restrict__ x, const float* __restrict__ h,
                               unsigned short* __restrict__ ap) {
  int idx = (blockIdx.x * blockDim.x + threadIdx.x) * 4;
  int row = idx >> 11;
  int k   = idx & 2047;
  const float* src = (k < 1024) ? (x + (size_t)row * 1024 + k)
                                : (h + (size_t)row * 1024 + (k - 1024));
  float4 v = *reinterpret_cast<const float4*>(src);
  int row16 = row >> 4, ll = row & 15;
  int kt = k >> 6, ks = (k >> 5) & 1, lg = (k >> 3) & 3, j0 = k & 7;  // j0 in {0,4}
  int lane = lg * 16 + ll;
  size_t off = (((size_t)row16 * 32 + kt) * 2 + ks) * 512 + lane * 8 + j0;
  ushort4 o = make_ushort4(f2bf(v.x), f2bf(v.y), f2bf(v.z), f2bf(v.w));
  *reinterpret_cast<ushort4*>(ap + off) = o;
}

// W[g] [2048][1024] f32 -> fragment-packed bf16 (same as R10):
// frag idx = (((kt*4 + g)*64 + gcf)*2 + ks)*64 + lane
// value[j] = W[kt*64 + ks*32 + (lane>>4)*8 + j][gcf*16 + (lane&15)]
__global__ void transpose_w4_kernel(const float* __restrict__ W0, const float* __restrict__ W1,
                                    const float* __restrict__ W2, const float* __restrict__ W3,
                                    unsigned short* __restrict__ wtp) {
  __shared__ float tile[32][33];
  const int g = blockIdx.z;
  const float* W = (g == 0) ? W0 : (g == 1) ? W1 : (g == 2) ? W2 : W3;
  int n0 = blockIdx.x * 32;
  int k0 = blockIdx.y * 32;
  int tx = threadIdx.x;
  int ty = threadIdx.y;
#pragma unroll
  for (int i = 0; i < 4; ++i)
    tile[ty + 8 * i][tx] = W[(size_t)(k0 + ty + 8 * i) * 1024 + (n0 + tx)];
  __syncthreads();
  int tid = ty * 32 + tx;
  if (tid < 128) {
    int col16 = tid & 15;
    int j2 = (tid >> 4) & 3;
    int gcf_sub = tid >> 6;
    int gcf = (n0 >> 4) + gcf_sub;
    int kt = k0 >> 6;
    int ks = (k0 >> 5) & 1;
    int lane = j2 * 16 + col16;
    bf16x8 v;
#pragma unroll
    for (int j = 0; j < 8; ++j)
      v[j] = (short)f2bf(tile[j2 * 8 + j][gcf_sub * 16 + col16]);
    size_t cid = ((((size_t)kt * 4 + g) * 64 + gcf) * 2 + ks) * 64 + lane;
    *reinterpret_cast<bf16x8*>(wtp + cid * 8) = v;
  }
}

#define LOADF(BASE, OFF) \
  (*reinterpret_cast<const bf16x8*>(reinterpret_cast<const char*>(BASE) + (OFF)))

// One K-tile: 4 gate MFMA clusters interleaved 1:1 with next-tile loads.
// CUR = aF for this tile; NXT gets tile T+1's aF (loaded at gate-1 slot).
#define TILE_BODY(T, CUR, NXT)                                                    \
  {                                                                               \
    const bool more = (T) < NT - 1;                                               \
    __builtin_amdgcn_s_setprio(1);                                                \
    _Pragma("unroll") for (int m = 0; m < 4; ++m)                                 \
        _Pragma("unroll") for (int n = 0; n < 2; ++n)                             \
            _Pragma("unroll") for (int ks = 0; ks < 2; ++ks)                      \
                acc[0][m][n] = __builtin_amdgcn_mfma_f32_16x16x32_bf16(           \
                    CUR[m][ks], bF[0][n][ks], acc[0][m][n], 0, 0, 0);             \
    __builtin_amdgcn_s_setprio(0);                                                \
    if (more) {                                                                   \
      _Pragma("unroll") for (int n = 0; n < 2; ++n)                               \
          _Pragma("unroll") for (int ks = 0; ks < 2; ++ks)                        \
              bF[0][n][ks] = LOADF(wtp, offB + 0u * 131072u + n * 2048u + ks * 1024u); \
    }                                                                             \
    __builtin_amdgcn_s_setprio(1);                                                \
    _Pragma("unroll") for (int m = 0; m < 4; ++m)                                 \
        _Pragma("unroll") for (int n = 0; n < 2; ++n)                             \
            _Pragma("unroll") for (int ks = 0; ks < 2; ++ks)                      \
                acc[1][m][n] = __builtin_amdgcn_mfma_f32_16x16x32_bf16(           \
                    CUR[m][ks], bF[1][n][ks], acc[1][m][n], 0, 0, 0);             \
    __builtin_amdgcn_s_setprio(0);                                                \
    if (more) {                                                                   \
      _Pragma("unroll") for (int n = 0; n < 2; ++n)                               \
          _Pragma("unroll") for (int ks = 0; ks < 2; ++ks)                        \
              bF[1][n][ks] = LOADF(wtp, offB + 1u * 131072u + n * 2048u + ks * 1024u); \
      _Pragma("unroll") for (int rf = 0; rf < 4; ++rf)                            \
          _Pragma("unroll") for (int ks = 0; ks < 2; ++ks)                        \
              NXT[rf][ks] = LOADF(ap, offA[rf] + ks * 1024u);                     \
    }                                                                             \
    __builtin_amdgcn_s_setprio(1);                                                \
    _Pragma("unroll") for (int m = 0; m < 4; ++m)                                 \
        _Pragma("unroll") for (int n = 0; n < 2; ++n)                             \
            _Pragma("unroll") for (int ks = 0; ks < 2; ++ks)                      \
                acc[2][m][n] = __builtin_amdgcn_mfma_f32_16x16x32_bf16(           \
                    CUR[m][ks], bF[2][n][ks], acc[2][m][n], 0, 0, 0);             \
    __builtin_amdgcn_s_setprio(0);                                                \
    if (more) {                                                                   \
      _Pragma("unroll") for (int n = 0; n < 2; ++n)                               \
          _Pragma("unroll") for (int ks = 0; ks < 2; ++ks)                        \
              bF[2][n][ks] = LOADF(wtp, offB + 2u * 131072u + n * 2048u + ks * 1024u); \
    }                                                                             \
    __builtin_amdgcn_s_setprio(1);                                                \
    _Pragma("unroll") for (int m = 0; m < 4; ++m)                                 \
        _Pragma("unroll") for (int n = 0; n < 2; ++n)                             \
            _Pragma("unroll") for (int ks = 0; ks < 2; ++ks)                      \
                acc[3][m][n] = __builtin_amdgcn_mfma_f32_16x16x32_bf16(           \
                    CUR[m][ks], bF[3][n][ks], acc[3][m][n], 0, 0, 0);             \
    __builtin_amdgcn_s_setprio(0);                                                \
    if (more) {                                                                   \
      _Pragma("unroll") for (int n = 0; n < 2; ++n)                               \
          _Pragma("unroll") for (int ks = 0; ks < 2; ++ks)                        \
              bF[3][n][ks] = LOADF(wtp, offB + 3u * 131072u + n * 2048u + ks * 1024u); \
      _Pragma("unroll") for (int rf = 0; rf < 4; ++rf) offA[rf] += 2048u;         \
      offB += 524288u;                                                            \
    }                                                                             \
  }

// Zero-sync flatmm LSTM: no LDS, no barriers; both operands direct global->VGPR.
// 512 blocks x 256 thr; wave = 64 rows x 32 cols x 4 gates, fully independent.
__global__ __launch_bounds__(256, 2) void lstm_fused_kernel(
    const unsigned short* __restrict__ ap,
    const unsigned short* __restrict__ wtp,
    const float* __restrict__ bias_f,
    const float* __restrict__ bias_i,
    const float* __restrict__ bias_s,
    const float* __restrict__ bias_p,
    const float* __restrict__ c_in,
    float* __restrict__ out) {
  const int tid  = threadIdx.x;
  const int lane = tid & 63;
  const int wid  = tid >> 6;   // 0..3 : 64-row slice within block
  const int lg   = lane >> 4;
  const int ll   = lane & 15;

  // XCD-chunked mapping: xcd owns 4 col-blocks (128 weight cols -> 2MB B panel in its L2)
  const int xcd = blockIdx.x & 7;
  const int s   = blockIdx.x >> 3;        // 0..63
  const int brow  = s >> 2;               // 0..15
  const int bcolw = xcd * 4 + (s & 3);    // 0..31

  // ---- byte offsets (uniform base + 32-bit voffset; imm folds n/ks) ----
  unsigned offA[4];
#pragma unroll
  for (int rf = 0; rf < 4; ++rf)
    offA[rf] = (unsigned)(brow * 16 + wid * 4 + rf) * 65536u + (unsigned)lane * 16u;
  unsigned offB = (unsigned)bcolw * 4096u + (unsigned)lane * 16u;

  f32x4 acc[4][4][2];
#pragma unroll
  for (int g = 0; g < 4; ++g)
#pragma unroll
    for (int m = 0; m < 4; ++m)
#pragma unroll
      for (int n = 0; n < 2; ++n)
        acc[g][m][n] = (f32x4)(0.0f);

  bf16x8 aFA[4][2], aFB[4][2], bF[4][2][2];

  // ---- prologue: load tile 0 (aFA + bF) ----
#pragma unroll
  for (int rf = 0; rf < 4; ++rf)
#pragma unroll
    for (int ks = 0; ks < 2; ++ks)
      aFA[rf][ks] = LOADF(ap, offA[rf] + ks * 1024u);
#pragma unroll
  for (int g = 0; g < 4; ++g)
#pragma unroll
    for (int n = 0; n < 2; ++n)
#pragma unroll
      for (int ks = 0; ks < 2; ++ks)
        bF[g][n][ks] = LOADF(wtp, offB + (unsigned)g * 131072u + n * 2048u + ks * 1024u);
#pragma unroll
  for (int rf = 0; rf < 4; ++rf) offA[rf] += 2048u;
  offB += 524288u;

  for (int t = 0; t < NT; t += 2) {
    TILE_BODY(t, aFA, aFB)
    TILE_BODY(t + 1, aFB, aFA)
  }

  // ---- epilogue: gates + cell update, store h_new (coalesced) ----
  const int row0 = brow * 256 + wid * 64;
  const int col0 = bcolw * 32;
  float bv[4][2];
#pragma unroll
  for (int n = 0; n < 2; ++n) {
    int col = col0 + n * 16 + ll;
    bv[0][n] = bias_f[col];
    bv[1][n] = bias_i[col];
    bv[2][n] = bias_s[col];
    bv[3][n] = bias_p[col];
  }
#pragma unroll
  for (int m = 0; m < 4; ++m)
#pragma unroll
    for (int n = 0; n < 2; ++n)
#pragma unroll
      for (int j = 0; j < 4; ++j) {
        int row = row0 + m * 16 + lg * 4 + j;
        int col = col0 + n * 16 + ll;
        float zf = acc[0][m][n][j] + bv[0][n];
        float zi = acc[1][m][n][j] + bv[1][n];
        float zs = acc[2][m][n][j] + bv[2][n];
        float zp = acc[3][m][n][j] + bv[3][n];
        float fg = sigm(zf);
        float ig = sigm(zi);
        float sg = sigm(zs);
        float pg = tanh_fast(zp);
        float cn = c_in[(size_t)row * 1024 + col] * fg + ig * pg;
        out[(size_t)row * 1024 + col] = tanh_fast(cn) * sg;
      }
}

extern "C" void kernel_launch(void* const* d_in, const int* in_sizes, int n_in,
                              void* d_out, int out_size, void* d_ws, size_t ws_size,
                              hipStream_t stream) {
  const float* x  = (const float*)d_in[0];
  const float* h  = (const float*)d_in[1];
  const float* c  = (const float*)d_in[2];
  const float* Wf = (const float*)d_in[3];
  const float* bf = (const float*)d_in[4];
  const float* Wi = (const float*)d_in[5];
  const float* bi = (const float*)d_in[6];
  const float* Ws = (const float*)d_in[7];
  const float* bs = (const float*)d_in[8];
  const float* Wp = (const float*)d_in[9];
  const float* bp = (const float*)d_in[10];
  float* out = (float*)d_out;

  unsigned short* ws = (unsigned short*)d_ws;
  unsigned short* ap  = ws;                        // packed hx fragments, 16 MB
  unsigned short* wtp = ws + (size_t)4096 * 2048;  // packed weight fragments, 16 MB

  pack_hx_kernel<<<(4096 * 2048 / 4) / 256, 256, 0, stream>>>(x, h, ap);

  dim3 tb(32, 8);
  dim3 tg(1024 / 32, 2048 / 32, 4);
  transpose_w4_kernel<<<tg, tb, 0, stream>>>(Wf, Wi, Ws, Wp, wtp);

  lstm_fused_kernel<<<512, 256, 0, stream>>>(ap, wtp, bf, bi, bs, bp, c, out);
}

// Round 12
// 100.035 us; speedup vs baseline: 1.5155x; 1.5155x over previous
//
#include <hip/hip_runtime.h>
#include <hip/hip_bf16.h>

typedef __attribute__((ext_vector_type(8))) short bf16x8;
typedef __attribute__((ext_vector_type(4))) float f32x4;

#define KDIM 2048
#define BK 64
#define NT (KDIM / BK)   // 32 K-tiles

__device__ __forceinline__ unsigned short f2bf(float f) {
  union { float fv; unsigned int u; } c; c.fv = f;
  unsigned int u = c.u;
  unsigned int r = (u + 0x7FFFu + ((u >> 16) & 1u)) >> 16;
  return (unsigned short)r;
}

__device__ __forceinline__ float sigm(float z) { return 1.0f / (1.0f + __expf(-z)); }
__device__ __forceinline__ float tanh_fast(float z) { return 1.0f - 2.0f / (__expf(2.0f * z) + 1.0f); }

// x,h f32 -> apack bf16 fragments:
// frag f = (row16*32 + kt)*2 + ks ; elem = f*512 + lane*8 + j ; lane = lg*16 + ll
// value = hx[row16*16 + ll][kt*64 + ks*32 + lg*8 + j]
__global__ void pack_hx_kernel(const float* __restrict__ x, const float* __restrict__ h,
                               unsigned short* __restrict__ ap) {
  int idx = (blockIdx.x * blockDim.x + threadIdx.x) * 4;
  int row = idx >> 11;
  int k   = idx & 2047;
  const float* src = (k < 1024) ? (x + (size_t)row * 1024 + k)
                                : (h + (size_t)row * 1024 + (k - 1024));
  float4 v = *reinterpret_cast<const float4*>(src);
  int row16 = row >> 4, ll = row & 15;
  int kt = k >> 6, ks = (k >> 5) & 1, lg = (k >> 3) & 3, j0 = k & 7;  // j0 in {0,4}
  int lane = lg * 16 + ll;
  size_t off = (((size_t)row16 * 32 + kt) * 2 + ks) * 512 + lane * 8 + j0;
  ushort4 o = make_ushort4(f2bf(v.x), f2bf(v.y), f2bf(v.z), f2bf(v.w));
  *reinterpret_cast<ushort4*>(ap + off) = o;
}

// W[g] [2048][1024] f32 -> fragment-packed bf16:
// frag idx = (((kt*4 + g)*64 + gcf)*2 + ks)*64 + lane
// value[j] = W[kt*64 + ks*32 + (lane>>4)*8 + j][gcf*16 + (lane&15)]
__global__ void transpose_w4_kernel(const float* __restrict__ W0, const float* __restrict__ W1,
                                    const float* __restrict__ W2, const float* __restrict__ W3,
                                    unsigned short* __restrict__ wtp) {
  __shared__ float tile[32][33];
  const int g = blockIdx.z;
  const float* W = (g == 0) ? W0 : (g == 1) ? W1 : (g == 2) ? W2 : W3;
  int n0 = blockIdx.x * 32;
  int k0 = blockIdx.y * 32;
  int tx = threadIdx.x;
  int ty = threadIdx.y;
#pragma unroll
  for (int i = 0; i < 4; ++i)
    tile[ty + 8 * i][tx] = W[(size_t)(k0 + ty + 8 * i) * 1024 + (n0 + tx)];
  __syncthreads();
  int tid = ty * 32 + tx;
  if (tid < 128) {
    int col16 = tid & 15;
    int j2 = (tid >> 4) & 3;
    int gcf_sub = tid >> 6;
    int gcf = (n0 >> 4) + gcf_sub;
    int kt = k0 >> 6;
    int ks = (k0 >> 5) & 1;
    int lane = j2 * 16 + col16;
    bf16x8 v;
#pragma unroll
    for (int j = 0; j < 8; ++j)
      v[j] = (short)f2bf(tile[j2 * 8 + j][gcf_sub * 16 + col16]);
    size_t cid = ((((size_t)kt * 4 + g) * 64 + gcf) * 2 + ks) * 64 + lane;
    *reinterpret_cast<bf16x8*>(wtp + cid * 8) = v;
  }
}

#define LOADF(BASE, OFF) \
  (*reinterpret_cast<const bf16x8*>(reinterpret_cast<const char*>(BASE) + (OFF)))

#define GATE_MFMA(G)                                                              \
  __builtin_amdgcn_s_setprio(1);                                                  \
  _Pragma("unroll") for (int m = 0; m < 4; ++m)                                   \
      _Pragma("unroll") for (int n = 0; n < 2; ++n)                               \
          _Pragma("unroll") for (int ks = 0; ks < 2; ++ks)                        \
              acc[G][m][n] = __builtin_amdgcn_mfma_f32_16x16x32_bf16(             \
                  aF[m][ks], bF[G][n][ks], acc[G][m][n], 0, 0, 0);                \
  __builtin_amdgcn_s_setprio(0);

#define RELOAD_B(G)                                                               \
  _Pragma("unroll") for (int n = 0; n < 2; ++n)                                   \
      _Pragma("unroll") for (int ks = 0; ks < 2; ++ks)                            \
          bF[G][n][ks] = LOADF(wtp, offB + (G) * 131072u + n * 2048u + ks * 1024u);

// Zero-sync flatmm LSTM: no LDS, no barriers; both operands direct global->VGPR.
// 512 blocks x 256 thr; wave = 64 rows x 32 cols x 4 gates, fully independent.
// Register budget: acc 128 (AGPR) + bF 64 + aF 32 + addr ~10 (arch VGPR <= 128).
__global__ __launch_bounds__(256, 2) void lstm_fused_kernel(
    const unsigned short* __restrict__ ap,
    const unsigned short* __restrict__ wtp,
    const float* __restrict__ bias_f,
    const float* __restrict__ bias_i,
    const float* __restrict__ bias_s,
    const float* __restrict__ bias_p,
    const float* __restrict__ c_in,
    float* __restrict__ out) {
  const int tid  = threadIdx.x;
  const int lane = tid & 63;
  const int wid  = tid >> 6;   // 0..3 : 64-row slice within block
  const int lg   = lane >> 4;
  const int ll   = lane & 15;

  // XCD-chunked mapping: each XCD owns 4 bcolw values -> 2MB B panel, L2-resident
  const int xcd = blockIdx.x & 7;
  const int s   = blockIdx.x >> 3;        // 0..63
  const int brow  = s >> 2;               // 0..15
  const int bcolw = xcd * 4 + (s & 3);    // 0..31

  // ---- byte offsets ----
  unsigned offA[4];
#pragma unroll
  for (int rf = 0; rf < 4; ++rf)
    offA[rf] = (unsigned)(brow * 16 + wid * 4 + rf) * 65536u + (unsigned)lane * 16u;
  unsigned offB = (unsigned)bcolw * 4096u + (unsigned)lane * 16u;

  f32x4 acc[4][4][2];
#pragma unroll
  for (int g = 0; g < 4; ++g)
#pragma unroll
    for (int m = 0; m < 4; ++m)
#pragma unroll
      for (int n = 0; n < 2; ++n)
        acc[g][m][n] = (f32x4)(0.0f);

  bf16x8 aF[4][2], bF[4][2][2];

  // ---- prologue: load tile 0 ----
#pragma unroll
  for (int rf = 0; rf < 4; ++rf)
#pragma unroll
    for (int ks = 0; ks < 2; ++ks)
      aF[rf][ks] = LOADF(ap, offA[rf] + ks * 1024u);
#pragma unroll
  for (int g = 0; g < 4; ++g) { RELOAD_B(g) }
#pragma unroll
  for (int rf = 0; rf < 4; ++rf) offA[rf] += 2048u;
  offB += 524288u;

  for (int t = 0; t < NT; ++t) {
    const bool more = (t < NT - 1);

    GATE_MFMA(0)
    if (more) { RELOAD_B(0) }
    GATE_MFMA(1)
    if (more) { RELOAD_B(1) }
    GATE_MFMA(2)
    if (more) { RELOAD_B(2) }
    GATE_MFMA(3)
    if (more) {
      RELOAD_B(3)
      // aF(t+1): gate3 (its last consumer) just finished -> safe to overwrite
#pragma unroll
      for (int rf = 0; rf < 4; ++rf)
#pragma unroll
        for (int ks = 0; ks < 2; ++ks)
          aF[rf][ks] = LOADF(ap, offA[rf] + ks * 1024u);
#pragma unroll
      for (int rf = 0; rf < 4; ++rf) offA[rf] += 2048u;
      offB += 524288u;
    }
  }

  // ---- epilogue: gates + cell update, store h_new (coalesced) ----
  const int row0 = brow * 256 + wid * 64;
  const int col0 = bcolw * 32;
  float bv[4][2];
#pragma unroll
  for (int n = 0; n < 2; ++n) {
    int col = col0 + n * 16 + ll;
    bv[0][n] = bias_f[col];
    bv[1][n] = bias_i[col];
    bv[2][n] = bias_s[col];
    bv[3][n] = bias_p[col];
  }
#pragma unroll
  for (int m = 0; m < 4; ++m)
#pragma unroll
    for (int n = 0; n < 2; ++n)
#pragma unroll
      for (int j = 0; j < 4; ++j) {
        int row = row0 + m * 16 + lg * 4 + j;
        int col = col0 + n * 16 + ll;
        float zf = acc[0][m][n][j] + bv[0][n];
        float zi = acc[1][m][n][j] + bv[1][n];
        float zs = acc[2][m][n][j] + bv[2][n];
        float zp = acc[3][m][n][j] + bv[3][n];
        float fg = sigm(zf);
        float ig = sigm(zi);
        float sg = sigm(zs);
        float pg = tanh_fast(zp);
        float cn = c_in[(size_t)row * 1024 + col] * fg + ig * pg;
        out[(size_t)row * 1024 + col] = tanh_fast(cn) * sg;
      }
}

extern "C" void kernel_launch(void* const* d_in, const int* in_sizes, int n_in,
                              void* d_out, int out_size, void* d_ws, size_t ws_size,
                              hipStream_t stream) {
  const float* x  = (const float*)d_in[0];
  const float* h  = (const float*)d_in[1];
  const float* c  = (const float*)d_in[2];
  const float* Wf = (const float*)d_in[3];
  const float* bf = (const float*)d_in[4];
  const float* Wi = (const float*)d_in[5];
  const float* bi = (const float*)d_in[6];
  const float* Ws = (const float*)d_in[7];
  const float* bs = (const float*)d_in[8];
  const float* Wp = (const float*)d_in[9];
  const float* bp = (const float*)d_in[10];
  float* out = (float*)d_out;

  unsigned short* ws = (unsigned short*)d_ws;
  unsigned short* ap  = ws;                        // packed hx fragments, 16 MB
  unsigned short* wtp = ws + (size_t)4096 * 2048;  // packed weight fragments, 16 MB

  pack_hx_kernel<<<(4096 * 2048 / 4) / 256, 256, 0, stream>>>(x, h, ap);

  dim3 tb(32, 8);
  dim3 tg(1024 / 32, 2048 / 32, 4);
  transpose_w4_kernel<<<tg, tb, 0, stream>>>(Wf, Wi, Ws, Wp, wtp);

  lstm_fused_kernel<<<512, 256, 0, stream>>>(ap, wtp, bf, bi, bs, bp, c, out);
}

// Round 13
// 87.718 us; speedup vs baseline: 1.7283x; 1.1404x over previous
//
#include <hip/hip_runtime.h>
#include <hip/hip_bf16.h>

typedef __attribute__((ext_vector_type(8))) short bf16x8;
typedef __attribute__((ext_vector_type(4))) float f32x4;

#define KDIM 2048
#define BK 64
#define NT (KDIM / BK)   // 32 K-tiles

__device__ __forceinline__ unsigned short f2bf(float f) {
  union { float fv; unsigned int u; } c; c.fv = f;
  unsigned int u = c.u;
  unsigned int r = (u + 0x7FFFu + ((u >> 16) & 1u)) >> 16;
  return (unsigned short)r;
}

__device__ __forceinline__ void gload_lds16(const unsigned short* g, unsigned short* l) {
  auto gp = reinterpret_cast<const __attribute__((address_space(1))) unsigned int*>(
      reinterpret_cast<uintptr_t>(g));
  auto lp = reinterpret_cast<__attribute__((address_space(3))) unsigned int*>(
      reinterpret_cast<uintptr_t>(l));
  __builtin_amdgcn_global_load_lds(gp, lp, 16, 0, 0);
}

__device__ __forceinline__ float sigm(float z) { return 1.0f / (1.0f + __expf(-z)); }
__device__ __forceinline__ float tanh_fast(float z) { return 1.0f - 2.0f / (__expf(2.0f * z) + 1.0f); }

// Build hx = [x | h] as bf16 [4096][2048]
__global__ void pack_hx_kernel(const float* __restrict__ x, const float* __restrict__ h,
                               unsigned short* __restrict__ hx) {
  int idx = (blockIdx.x * blockDim.x + threadIdx.x) * 4;
  int row = idx >> 11;
  int col = idx & 2047;
  const float* src = (col < 1024) ? (x + (size_t)row * 1024 + col)
                                  : (h + (size_t)row * 1024 + (col - 1024));
  float4 v = *reinterpret_cast<const float4*>(src);
  ushort4 o = make_ushort4(f2bf(v.x), f2bf(v.y), f2bf(v.z), f2bf(v.w));
  *reinterpret_cast<ushort4*>(hx + idx) = o;
}

// All four W [2048][1024] f32 -> Wt [4][1024][2048] bf16 in one launch (z = gate)
__global__ void transpose_w4_kernel(const float* __restrict__ W0, const float* __restrict__ W1,
                                    const float* __restrict__ W2, const float* __restrict__ W3,
                                    unsigned short* __restrict__ Wt) {
  __shared__ float tile[32][33];
  const int g = blockIdx.z;
  const float* W = (g == 0) ? W0 : (g == 1) ? W1 : (g == 2) ? W2 : W3;
  unsigned short* T = Wt + (size_t)g * 1024 * 2048;
  int n0 = blockIdx.x * 32;
  int k0 = blockIdx.y * 32;
  int tx = threadIdx.x;
  int ty = threadIdx.y;
#pragma unroll
  for (int i = 0; i < 4; ++i)
    tile[ty + 8 * i][tx] = W[(size_t)(k0 + ty + 8 * i) * 1024 + (n0 + tx)];
  __syncthreads();
#pragma unroll
  for (int i = 0; i < 4; ++i)
    T[(size_t)(n0 + ty + 8 * i) * 2048 + (k0 + tx)] = f2bf(tile[tx][ty + 8 * i]);
}

// ---- m201-combo sync primitives: BUILTIN barrier + asm counted waits, no sched pins ----
#define BARR __builtin_amdgcn_s_barrier()
#define LGKM0 asm volatile("s_waitcnt lgkmcnt(0)" ::: "memory")
#define LGKM8 asm volatile("s_waitcnt lgkmcnt(8)" ::: "memory")
#define VMC(N) asm volatile("s_waitcnt vmcnt(" #N ")" ::: "memory")

#define MFMA_Q(MH, AFR, GB)                                                       \
  __builtin_amdgcn_s_setprio(1);                                                  \
  _Pragma("unroll") for (int m = 0; m < 4; ++m)                                   \
    _Pragma("unroll") for (int gg = 0; gg < 2; ++gg)                              \
      _Pragma("unroll") for (int ks = 0; ks < 2; ++ks)                            \
        acc[(MH)*4 + m][(GB) + gg] = __builtin_amdgcn_mfma_f32_16x16x32_bf16(     \
            AFR[m][ks], bF[gg][ks], acc[(MH)*4 + m][(GB) + gg], 0, 0, 0);         \
  __builtin_amdgcn_s_setprio(0);

// Fused 4-gate GEMM + LSTM epilogue — verbatim m201 8-phase skeleton.
// Grid: 256 blocks (1/CU), 512 threads (8 waves: 2 wr x 4 wc).
// Wave: 128 rows x 16 cols x 4 gates. Block: 256 rows x 64 cols x 4 gates.
__global__ __launch_bounds__(512, 2) void lstm_fused_kernel(
    const unsigned short* __restrict__ hx,
    const unsigned short* __restrict__ wtb,
    const float* __restrict__ bias_f,
    const float* __restrict__ bias_i,
    const float* __restrict__ bias_s,
    const float* __restrict__ bias_p,
    const float* __restrict__ c_in,
    float* __restrict__ out) {
  __shared__ unsigned short lA[2][256 * BK];  // 2 x 32 KB : rows 0..255
  __shared__ unsigned short lB[2][256 * BK];  // 2 x 32 KB : row = gate*64 + col

  const int tid  = threadIdx.x;
  const int lane = tid & 63;
  const int wid  = tid >> 6;
  const int wr   = wid >> 2;  // 0..1 : 128-row slice
  const int wc   = wid & 3;   // 0..3 : 16-col slice
  const int lg   = lane >> 4;
  const int ll   = lane & 15;

  // bijective XCD swizzle (256 % 8 == 0)
  const int wg   = (blockIdx.x & 7) * 32 + (blockIdx.x >> 3);
  const int brow = wg >> 4;  // 0..15
  const int bcol = wg & 15;  // 0..15

  // ---- staging descriptors: load i covers 64 rows (i*64..), 8KB each ----
  const unsigned short* srcA[4];
  const unsigned short* srcB[4];
  unsigned int dA[4], dB[4];
  {
    int r_lo = tid >> 3, sch = tid & 7;
    int ch = sch ^ (r_lo & 7);  // inverse swizzle on global source
#pragma unroll
    for (int i = 0; i < 4; ++i) {
      srcA[i] = hx + (size_t)(brow * 256 + i * 64 + r_lo) * KDIM + ch * 8;
      srcB[i] = wtb + (size_t)i * 1024 * 2048 + (size_t)(bcol * 64 + r_lo) * KDIM + ch * 8;
      dA[i] = i * 4096 + tid * 8;
      dB[i] = i * 4096 + tid * 8;
    }
  }

  // ---- fragment LDS element offsets ----
  const int ch0 = lg ^ (ll & 7);
  const int ch1 = (4 + lg) ^ (ll & 7);
  const unsigned aBase = (unsigned)((wr * 128 + ll) * 64);
  const unsigned bBase = (unsigned)((wc * 16 + ll) * 64);

  f32x4 acc[8][4];
#pragma unroll
  for (int mi = 0; mi < 8; ++mi)
#pragma unroll
    for (int g = 0; g < 4; ++g)
      acc[mi][g] = (f32x4)(0.0f);

  // ---- prologue: stage tile 0 (c-order: A02, B01, A13, B23), drain, barrier ----
  gload_lds16(srcA[0], &lA[0][dA[0]]);
  gload_lds16(srcA[2], &lA[0][dA[2]]);
  gload_lds16(srcB[0], &lB[0][dB[0]]);
  gload_lds16(srcB[1], &lB[0][dB[1]]);
  gload_lds16(srcA[1], &lA[0][dA[1]]);
  gload_lds16(srcA[3], &lA[0][dA[3]]);
  gload_lds16(srcB[2], &lB[0][dB[2]]);
  gload_lds16(srcB[3], &lB[0][dB[3]]);
#pragma unroll
  for (int i = 0; i < 4; ++i) { srcA[i] += BK; srcB[i] += BK; }
  VMC(0);
  BARR;

  for (int t = 0; t < NT; ++t) {
    const int p = t & 1;
    const unsigned short* Ab = &lA[p][0];
    const unsigned short* Bb = &lB[p][0];
    unsigned short* An = &lA[p ^ 1][0];
    unsigned short* Bn = &lB[p ^ 1][0];
    const bool stg = (t < NT - 1);

    bf16x8 aF0[4][2], aF1[4][2], bF[2][2];

    // ---------- ph0: read aF0(8) + bF01(4); stage A-H0(t+1); MFMA Q(mh0,g01) ----------
#pragma unroll
    for (int m = 0; m < 4; ++m) {
      aF0[m][0] = *reinterpret_cast<const bf16x8*>(Ab + aBase + m * 1024 + ch0 * 8);
      aF0[m][1] = *reinterpret_cast<const bf16x8*>(Ab + aBase + m * 1024 + ch1 * 8);
    }
#pragma unroll
    for (int gg = 0; gg < 2; ++gg) {
      bF[gg][0] = *reinterpret_cast<const bf16x8*>(Bb + bBase + gg * 4096 + ch0 * 8);
      bF[gg][1] = *reinterpret_cast<const bf16x8*>(Bb + bBase + gg * 4096 + ch1 * 8);
    }
    if (stg) { gload_lds16(srcA[0], An + dA[0]); gload_lds16(srcA[2], An + dA[2]); }
    LGKM8;  // 12 ds_reads issued this phase (template's optional throttle)
    BARR;
    LGKM0;
    MFMA_Q(0, aF0, 0)
    if (stg) { VMC(2); } else { VMC(0); }
    BARR;

    // ---------- ph1: read aF1(8); stage B-H0(t+1); MFMA Q(mh1,g01) ----------
#pragma unroll
    for (int m = 0; m < 4; ++m) {
      aF1[m][0] = *reinterpret_cast<const bf16x8*>(Ab + aBase + 4096 + m * 1024 + ch0 * 8);
      aF1[m][1] = *reinterpret_cast<const bf16x8*>(Ab + aBase + 4096 + m * 1024 + ch1 * 8);
    }
    if (stg) { gload_lds16(srcB[0], Bn + dB[0]); gload_lds16(srcB[1], Bn + dB[1]); }
    BARR;
    LGKM0;
    MFMA_Q(1, aF1, 0)
    BARR;

    // ---------- ph2: read bF23(4); stage A-H1(t+1); MFMA Q(mh1,g23) ----------
#pragma unroll
    for (int gg = 0; gg < 2; ++gg) {
      bF[gg][0] = *reinterpret_cast<const bf16x8*>(Bb + bBase + (2 + gg) * 4096 + ch0 * 8);
      bF[gg][1] = *reinterpret_cast<const bf16x8*>(Bb + bBase + (2 + gg) * 4096 + ch1 * 8);
    }
    if (stg) { gload_lds16(srcA[1], An + dA[1]); gload_lds16(srcA[3], An + dA[3]); }
    BARR;
    LGKM0;
    MFMA_Q(1, aF1, 2)
    BARR;

    // ---------- ph3: stage B-H1(t+1); MFMA Q(mh0,g23); vmcnt(4) ----------
    if (stg) { gload_lds16(srcB[2], Bn + dB[2]); gload_lds16(srcB[3], Bn + dB[3]); }
    BARR;
    LGKM0;
    MFMA_Q(0, aF0, 2)
    if (stg) { VMC(4); }
    BARR;

    if (stg) {
#pragma unroll
      for (int i = 0; i < 4; ++i) { srcA[i] += BK; srcB[i] += BK; }
    }
  }

  // ---- epilogue: gates + cell update, store h_new (coalesced) ----
  const int col = bcol * 64 + wc * 16 + ll;
  const float bv0 = bias_f[col];
  const float bv1 = bias_i[col];
  const float bv2 = bias_s[col];
  const float bv3 = bias_p[col];
#pragma unroll
  for (int mi = 0; mi < 8; ++mi) {
    const int rbase = brow * 256 + wr * 128 + (mi >> 2) * 64 + (mi & 3) * 16 + lg * 4;
#pragma unroll
    for (int j = 0; j < 4; ++j) {
      int row = rbase + j;
      float zf = acc[mi][0][j] + bv0;
      float zi = acc[mi][1][j] + bv1;
      float zs = acc[mi][2][j] + bv2;
      float zp = acc[mi][3][j] + bv3;
      float fg = sigm(zf);
      float ig = sigm(zi);
      float sg = sigm(zs);
      float pg = tanh_fast(zp);
      float cn = c_in[(size_t)row * 1024 + col] * fg + ig * pg;
      out[(size_t)row * 1024 + col] = tanh_fast(cn) * sg;
    }
  }
}

extern "C" void kernel_launch(void* const* d_in, const int* in_sizes, int n_in,
                              void* d_out, int out_size, void* d_ws, size_t ws_size,
                              hipStream_t stream) {
  const float* x  = (const float*)d_in[0];
  const float* h  = (const float*)d_in[1];
  const float* c  = (const float*)d_in[2];
  const float* Wf = (const float*)d_in[3];
  const float* bf = (const float*)d_in[4];
  const float* Wi = (const float*)d_in[5];
  const float* bi = (const float*)d_in[6];
  const float* Ws = (const float*)d_in[7];
  const float* bs = (const float*)d_in[8];
  const float* Wp = (const float*)d_in[9];
  const float* bp = (const float*)d_in[10];
  float* out = (float*)d_out;

  unsigned short* ws = (unsigned short*)d_ws;
  unsigned short* hx  = ws;                        // 4096*2048 bf16 = 16 MB
  unsigned short* wtb = ws + (size_t)4096 * 2048;  // 4*1024*2048 bf16 = 16 MB

  pack_hx_kernel<<<(4096 * 2048 / 4) / 256, 256, 0, stream>>>(x, h, hx);

  dim3 tb(32, 8);
  dim3 tg(1024 / 32, 2048 / 32, 4);
  transpose_w4_kernel<<<tg, tb, 0, stream>>>(Wf, Wi, Ws, Wp, wtb);

  lstm_fused_kernel<<<256, 512, 0, stream>>>(hx, wtb, bf, bi, bs, bp, c, out);
}